// Round 10
// baseline (132.445 us; speedup 1.0000x reference)
//
#include <hip/hip_runtime.h>
#include <hip/hip_bf16.h>

// Problem constants (fixed by the reference): B=4, H=16, S=1024, D=64.
#define B_N 4
#define H_N 16
#define S_N 1024
#define D_N 64
#define NELEM (B_N * H_N * S_N * D_N)   // 4194304 elements per tensor

typedef __bf16 bf16;
typedef bf16  bf16x4 __attribute__((ext_vector_type(4)));
typedef bf16  bf16x8 __attribute__((ext_vector_type(8)));
typedef float f32x4  __attribute__((ext_vector_type(4)));
typedef unsigned int u32x2 __attribute__((ext_vector_type(2)));

#define AS1 __attribute__((address_space(1)))
#define AS3 __attribute__((address_space(3)))
// global->LDS DMA, 16B per lane; LDS dest = wave-uniform base + lane*16 (m104)
#define GLL16(gp, lp) __builtin_amdgcn_global_load_lds((const AS1 void*)(gp), (AS3 void*)(lp), 16, 0, 0)

// ============================================================================
// Prep (one kernel): fp32 -> bf16 swizzled copies of K and V into d_ws.
//  Kb[bh][k][d]  16B slots within each 128B row XORed by (k&7)
//  Vt[bh][d][k]  transposed; within each 64-k chunk, slots XORed by (d&7)
// ============================================================================
__global__ __launch_bounds__(256)
void prep_kv(const float* __restrict__ K, const float* __restrict__ V,
             bf16* __restrict__ Kb, bf16* __restrict__ Vt)
{
    const int b = blockIdx.x;
    if (b < 2048) {                        // ---- K: swizzled bf16 copy ----
        int t = b * 256 + threadIdx.x;     // 8 elems per thread
        int row = t >> 3, sub = t & 7;     // row = bh*S + k; sub = 16B slot
        const float* src = K + (size_t)row * 64 + sub * 8;
        float4 f0 = *(const float4*)src;
        float4 f1 = *(const float4*)(src + 4);
        bf16x8 o;
        o[0] = (bf16)f0.x; o[1] = (bf16)f0.y; o[2] = (bf16)f0.z; o[3] = (bf16)f0.w;
        o[4] = (bf16)f1.x; o[5] = (bf16)f1.y; o[6] = (bf16)f1.z; o[7] = (bf16)f1.w;
        int slot = sub ^ (row & 7);
        *(bf16x8*)(Kb + (size_t)row * 64 + slot * 8) = o;
    } else {                               // ---- V: transpose + swizzle ----
        int wid  = (b - 2048) * 4 + (threadIdx.x >> 6);
        int lane = threadIdx.x & 63;       // lane = d
        int bh = wid >> 7, chunk = wid & 127;   // 128 chunks of 8 k-rows
        const float* src = V + (size_t)bh * S_N * D_N + (size_t)chunk * 8 * 64 + lane;
        bf16x8 o;
#pragma unroll
        for (int j = 0; j < 8; ++j) o[j] = (bf16)src[j * 64];
        int slot = (chunk & 7) ^ (lane & 7);
        bf16* dst = Vt + (size_t)bh * D_N * S_N + (size_t)lane * S_N
                       + (chunk >> 3) * 64 + slot * 8;
        *(bf16x8*)dst = o;
    }
}

// ============================================================================
// Main fused kernel: 1 block = 64 q-rows (4 waves x 16).
// Round 10: SINGLE QK^T pass. Phase 1 computes scores, exp, row-sums and
// caches unnormalized bf16(exp(s)) in VGPRs (bf16x4 pc[16][4] = 128 VGPRs,
// fully unrolled -> static indexing). Phase 2 stages only V: normalize from
// the register cache, Pt_lds roundtrip (tr_read), PV MFMA, P/O stores.
// Eliminates: 2nd K staging (8MB/block-set), half the MFMAs, half the expf.
// ============================================================================
__global__ __launch_bounds__(256)
void sdpa_main(const float* __restrict__ Qf, const bf16* __restrict__ Kb,
               const bf16* __restrict__ Vt, float* __restrict__ Og,
               float* __restrict__ Pg)
{
    __shared__ __attribute__((aligned(128))) bf16 K_lds[2][4096];   // 16KB
    __shared__ __attribute__((aligned(128))) bf16 V_lds[2][4096];   // 16KB
    __shared__ __attribute__((aligned(128))) bf16 Pt_lds[4][1024];  // 8KB

    // XCD-bijective swizzle: 16 q-tiles of each bh land on one XCD (nwg=1024%8==0)
    const int bid = blockIdx.x;
    const int swz = (bid & 7) * 128 + (bid >> 3);
    const int bh = swz >> 4, qtile = swz & 15;

    const int tid = threadIdx.x;
    const int wave = tid >> 6, lane = tid & 63;
    const int l16 = lane & 15, lgrp = lane >> 4;
    const int swx = (l16 & 7) << 4;     // byte XOR for swizzled LDS reads

    const float* Qp = Qf + (size_t)bh * S_N * D_N;
    const bf16* Kp = Kb + (size_t)bh * S_N * D_N;
    const bf16* Vp = Vt + (size_t)bh * D_N * S_N;
    float* Op = Og + (size_t)bh * S_N * D_N;
    float* Pp = Pg + (size_t)bh * S_N * S_N;

    // Q A-fragments from fp32, scaled by 1/sqrt(64): a[j]=Q[q=l16][k=lgrp*8+j]
    const int qrow = qtile * 64 + wave * 16 + l16;
    bf16x8 aq[2];
#pragma unroll
    for (int ds = 0; ds < 2; ++ds) {
        const float* src = Qp + (size_t)qrow * 64 + ds * 32 + lgrp * 8;
        float4 f0 = *(const float4*)src;
        float4 f1 = *(const float4*)(src + 4);
        aq[ds][0] = (bf16)(f0.x * 0.125f); aq[ds][1] = (bf16)(f0.y * 0.125f);
        aq[ds][2] = (bf16)(f0.z * 0.125f); aq[ds][3] = (bf16)(f0.w * 0.125f);
        aq[ds][4] = (bf16)(f1.x * 0.125f); aq[ds][5] = (bf16)(f1.y * 0.125f);
        aq[ds][6] = (bf16)(f1.z * 0.125f); aq[ds][7] = (bf16)(f1.w * 0.125f);
    }

    // Staging: one 64x64 bf16 tile = 8KB = 2 GLL16 per wave (4 waves)
    auto stage_k = [&](int kt, bf16* dst) {
        const bf16* gk = Kp + (size_t)kt * 64;
        GLL16(gk + (wave    ) * 512 + lane * 8, dst + (wave    ) * 512);
        GLL16(gk + (wave + 4) * 512 + lane * 8, dst + (wave + 4) * 512);
    };
    auto stage_v = [&](int kt, bf16* dst) {
        const int dr = lane >> 3, c7 = lane & 7;   // rows are d, 128B slices
        GLL16(Vp + (size_t)((wave    ) * 8 + dr) * S_N + kt + c7 * 8, dst + (wave    ) * 512);
        GLL16(Vp + (size_t)((wave + 4) * 8 + dr) * S_N + kt + c7 * 8, dst + (wave + 4) * 512);
    };

    // QK^T scores for this wave's 16 q-rows vs a staged 64-row K tile.
    // C/D layout (m89): col(k) = lane&15, row(q) = (lane>>4)*4 + reg.
    auto scores = [&](const bf16* base, f32x4 (&acc)[4]) {
#pragma unroll
        for (int kb = 0; kb < 4; ++kb) {
            acc[kb] = (f32x4){0.f, 0.f, 0.f, 0.f};
#pragma unroll
            for (int ds = 0; ds < 2; ++ds) {
                bf16x8 bk = *(const bf16x8*)((const char*)base
                            + (kb * 16 + l16) * 128
                            + ((ds * 64 + lgrp * 16) ^ swx));
                acc[kb] = __builtin_amdgcn_mfma_f32_16x16x32_bf16(aq[ds], bk, acc[kb], 0, 0, 0);
            }
        }
    };

    // Register cache of unnormalized exp(s), bf16-packed.
    // pc[t][kb][r] = exp(score) for q = wave*16 + lgrp*4 + r, k = t*64+kb*16+l16.
    // Fully static indexing (loops unrolled) -> stays in VGPRs (128).
    bf16x4 pc[16][4];

    // -------- Phase 1: single QK^T pass: exp, row-sums, cache ---------------
    float lsum[4] = {0.f, 0.f, 0.f, 0.f};
    stage_k(0, &K_lds[0][0]);
    __syncthreads();
#pragma unroll
    for (int t = 0; t < 16; ++t) {
        const int buf = t & 1;
        if (t < 15) stage_k((t + 1) * 64, &K_lds[buf ^ 1][0]);  // hide under compute
        if (t == 15) stage_v(0, &V_lds[0][0]);                  // pre-stage V tile 0
        f32x4 acc[4];
        scores(&K_lds[buf][0], acc);
#pragma unroll
        for (int kb = 0; kb < 4; ++kb) {
            bf16x4 pk;
#pragma unroll
            for (int r = 0; r < 4; ++r) {
                float e = __expf(acc[kb][r]);
                lsum[r] += e;
                pk[r] = (bf16)e;
            }
            pc[t][kb] = pk;
        }
        __syncthreads();   // joins waves AND drains vmcnt -> prefetch complete
    }
    float rl[4];
#pragma unroll
    for (int r = 0; r < 4; ++r) {
        float s = lsum[r];
        s += __shfl_xor(s, 1, 64);
        s += __shfl_xor(s, 2, 64);
        s += __shfl_xor(s, 4, 64);
        s += __shfl_xor(s, 8, 64);
        rl[r] = 1.0f / s;
    }

    // -------- Phase 2: normalize from cache, PV, write P/O (V-only staging) -
    f32x4 oacc[4];
#pragma unroll
    for (int db = 0; db < 4; ++db) oacc[db] = (f32x4){0.f, 0.f, 0.f, 0.f};

    const unsigned ptoff = (unsigned)(uintptr_t)(AS3 bf16*)(&Pt_lds[wave][0]);
    const int qg = qtile * 64 + wave * 16 + l16;

#pragma unroll
    for (int t = 0; t < 16; ++t) {
        const int kt = t * 64, buf = t & 1;
        if (t < 15) stage_v(kt + 64, &V_lds[buf ^ 1][0]);

        // p = bf16(e) * rl -> bf16; write P^T[k][q] as packed 4-q ds_write_b64
#pragma unroll
        for (int kb = 0; kb < 4; ++kb) {
            bf16x4 pk;
#pragma unroll
            for (int r = 0; r < 4; ++r)
                pk[r] = (bf16)((float)pc[t][kb][r] * rl[r]);
            *(bf16x4*)((char*)&Pt_lds[wave][0] + (kb * 16 + l16) * 32 + lgrp * 8) = pk;
        }
        asm volatile("s_waitcnt lgkmcnt(0)" ::: "memory");  // writes done before tr reads

        const bf16* vb = &V_lds[buf][0];
#pragma unroll
        for (int ks = 0; ks < 2; ++ks) {
            // V B-fragments (swizzled row-major [d][k] reads, 2-way free)
            bf16x8 bv0 = *(const bf16x8*)((const char*)vb + (l16     ) * 128 + ((ks * 64 + lgrp * 16) ^ swx));
            bf16x8 bv1 = *(const bf16x8*)((const char*)vb + (16 + l16) * 128 + ((ks * 64 + lgrp * 16) ^ swx));
            bf16x8 bv2 = *(const bf16x8*)((const char*)vb + (32 + l16) * 128 + ((ks * 64 + lgrp * 16) ^ swx));
            bf16x8 bv3 = *(const bf16x8*)((const char*)vb + (48 + l16) * 128 + ((ks * 64 + lgrp * 16) ^ swx));

            // PV A-fragment via HW transpose read (region per 16-lane group,
            // per-lane addr slot (addr&127)>>3 picks column q=l16).
            u32x2 t0, t1;
            unsigned a = ptoff + ks * 1024 + lgrp * 256 + l16 * 8;
            asm volatile("ds_read_b64_tr_b16 %0, %2\n\t"
                         "ds_read_b64_tr_b16 %1, %2 offset:128"
                         : "=&v"(t0), "=&v"(t1) : "v"(a));
            asm volatile("s_waitcnt lgkmcnt(0)" ::: "memory");
            __builtin_amdgcn_sched_barrier(0);   // rule 18: keep MFMA below the wait

            bf16x8 ap;
            ((unsigned*)&ap)[0] = t0[0]; ((unsigned*)&ap)[1] = t0[1];
            ((unsigned*)&ap)[2] = t1[0]; ((unsigned*)&ap)[3] = t1[1];

            // Global P store: lane holds 8 contiguous k for row q=l16 -> 2x f32x4
            float4 o0, o1;
            o0.x = __uint_as_float(t0[0] << 16);
            o0.y = __uint_as_float(t0[0] & 0xffff0000u);
            o0.z = __uint_as_float(t0[1] << 16);
            o0.w = __uint_as_float(t0[1] & 0xffff0000u);
            o1.x = __uint_as_float(t1[0] << 16);
            o1.y = __uint_as_float(t1[0] & 0xffff0000u);
            o1.z = __uint_as_float(t1[1] << 16);
            o1.w = __uint_as_float(t1[1] & 0xffff0000u);
            float* pp = Pp + (size_t)qg * S_N + kt + ks * 32 + lgrp * 8;
            *(float4*)pp = o0;
            *(float4*)(pp + 4) = o1;

            oacc[0] = __builtin_amdgcn_mfma_f32_16x16x32_bf16(ap, bv0, oacc[0], 0, 0, 0);
            oacc[1] = __builtin_amdgcn_mfma_f32_16x16x32_bf16(ap, bv1, oacc[1], 0, 0, 0);
            oacc[2] = __builtin_amdgcn_mfma_f32_16x16x32_bf16(ap, bv2, oacc[2], 0, 0, 0);
            oacc[3] = __builtin_amdgcn_mfma_f32_16x16x32_bf16(ap, bv3, oacc[3], 0, 0, 0);
        }
        __syncthreads();   // joins waves AND drains vmcnt -> prefetch complete
    }

    const int qb0 = qtile * 64 + wave * 16 + lgrp * 4;
#pragma unroll
    for (int db = 0; db < 4; ++db)
#pragma unroll
        for (int r = 0; r < 4; ++r)
            Op[(size_t)(qb0 + r) * D_N + db * 16 + l16] = oacc[db][r];
}

// ============================================================================
// Round-1 fallback (fp32 inputs, no workspace) — used only if ws too small.
// ============================================================================
__global__ __launch_bounds__(256)
void sdpa_fused(const float* __restrict__ Qg, const float* __restrict__ Kg,
                const float* __restrict__ Vg, float* __restrict__ Og,
                float* __restrict__ Pg)
{
    constexpr int LDP = 72;
    __shared__ bf16 K_lds [64][LDP];
    __shared__ bf16 Vt_lds[64][LDP];
    __shared__ bf16 P_lds [4][16][LDP];

    const int qtile = blockIdx.x;
    const int bh    = blockIdx.y;
    const int tid   = threadIdx.x;
    const int wave  = tid >> 6;
    const int lane  = tid & 63;
    const int l16   = lane & 15;
    const int lgrp  = lane >> 4;

    const float* Qp = Qg + (size_t)bh * S_N * D_N;
    const float* Kp = Kg + (size_t)bh * S_N * D_N;
    const float* Vp = Vg + (size_t)bh * S_N * D_N;
    float* Op = Og + (size_t)bh * S_N * D_N;
    float* Pp = Pg + (size_t)bh * S_N * S_N;

    const int qrow = qtile * 64 + wave * 16 + l16;
    bf16x8 aq[2];
#pragma unroll
    for (int ds = 0; ds < 2; ++ds) {
        const float* src = Qp + qrow * D_N + ds * 32 + lgrp * 8;
        float4 f0 = *(const float4*)(src);
        float4 f1 = *(const float4*)(src + 4);
        aq[ds][0] = (bf16)(f0.x * 0.125f); aq[ds][1] = (bf16)(f0.y * 0.125f);
        aq[ds][2] = (bf16)(f0.z * 0.125f); aq[ds][3] = (bf16)(f0.w * 0.125f);
        aq[ds][4] = (bf16)(f1.x * 0.125f); aq[ds][5] = (bf16)(f1.y * 0.125f);
        aq[ds][6] = (bf16)(f1.z * 0.125f); aq[ds][7] = (bf16)(f1.w * 0.125f);
    }

    auto stage_k = [&](int kt) {
#pragma unroll
        for (int i = 0; i < 4; ++i) {
            int slot = tid + i * 256;
            int row = slot >> 4, c4 = slot & 15;
            float4 f = *(const float4*)(Kp + (kt + row) * D_N + c4 * 4);
            bf16x4 pk = {(bf16)f.x, (bf16)f.y, (bf16)f.z, (bf16)f.w};
            *(bf16x4*)&K_lds[row][c4 * 4] = pk;
        }
    };
    auto stage_v = [&](int kt) {
#pragma unroll
        for (int i = 0; i < 4; ++i) {
            int slot = tid + i * 256;
            int row = slot >> 4, c4 = slot & 15;
            float4 f = *(const float4*)(Vp + (kt + row) * D_N + c4 * 4);
            Vt_lds[c4 * 4 + 0][row] = (bf16)f.x;
            Vt_lds[c4 * 4 + 1][row] = (bf16)f.y;
            Vt_lds[c4 * 4 + 2][row] = (bf16)f.z;
            Vt_lds[c4 * 4 + 3][row] = (bf16)f.w;
        }
    };
    auto compute_scores = [&](f32x4 (&acc)[4]) {
#pragma unroll
        for (int kb = 0; kb < 4; ++kb) {
            acc[kb] = (f32x4){0.f, 0.f, 0.f, 0.f};
#pragma unroll
            for (int ds = 0; ds < 2; ++ds) {
                bf16x8 bk = *(const bf16x8*)&K_lds[kb * 16 + l16][ds * 32 + lgrp * 8];
                acc[kb] = __builtin_amdgcn_mfma_f32_16x16x32_bf16(aq[ds], bk, acc[kb], 0, 0, 0);
            }
        }
    };

    float lsum[4] = {0.f, 0.f, 0.f, 0.f};
    for (int kt = 0; kt < S_N; kt += 64) {
        __syncthreads();
        stage_k(kt);
        __syncthreads();
        f32x4 acc[4];
        compute_scores(acc);
#pragma unroll
        for (int kb = 0; kb < 4; ++kb)
#pragma unroll
            for (int r = 0; r < 4; ++r) lsum[r] += __expf(acc[kb][r]);
    }
    float rl[4];
#pragma unroll
    for (int r = 0; r < 4; ++r) {
        float s = lsum[r];
        s += __shfl_xor(s, 1, 64);
        s += __shfl_xor(s, 2, 64);
        s += __shfl_xor(s, 4, 64);
        s += __shfl_xor(s, 8, 64);
        rl[r] = 1.0f / s;
    }

    f32x4 oacc[4];
#pragma unroll
    for (int db = 0; db < 4; ++db) oacc[db] = (f32x4){0.f, 0.f, 0.f, 0.f};
    const int qb0 = qtile * 64 + wave * 16 + lgrp * 4;

    for (int kt = 0; kt < S_N; kt += 64) {
        __syncthreads();
        stage_k(kt);
        stage_v(kt);
        __syncthreads();

        f32x4 acc[4];
        compute_scores(acc);
#pragma unroll
        for (int kb = 0; kb < 4; ++kb) {
#pragma unroll
            for (int r = 0; r < 4; ++r) {
                float p = __expf(acc[kb][r]) * rl[r];
                Pp[(size_t)(qb0 + r) * S_N + (kt + kb * 16 + l16)] = p;
                P_lds[wave][lgrp * 4 + r][kb * 16 + l16] = (bf16)p;
            }
        }
#pragma unroll
        for (int ks = 0; ks < 2; ++ks) {
            bf16x8 ap = *(const bf16x8*)&P_lds[wave][l16][ks * 32 + lgrp * 8];
#pragma unroll
            for (int db = 0; db < 4; ++db) {
                bf16x8 bv = *(const bf16x8*)&Vt_lds[db * 16 + l16][ks * 32 + lgrp * 8];
                oacc[db] = __builtin_amdgcn_mfma_f32_16x16x32_bf16(ap, bv, oacc[db], 0, 0, 0);
            }
        }
    }

#pragma unroll
    for (int db = 0; db < 4; ++db)
#pragma unroll
        for (int r = 0; r < 4; ++r)
            Op[(size_t)(qb0 + r) * D_N + db * 16 + l16] = oacc[db][r];
}

extern "C" void kernel_launch(void* const* d_in, const int* in_sizes, int n_in,
                              void* d_out, int out_size, void* d_ws, size_t ws_size,
                              hipStream_t stream) {
    const float* Q = (const float*)d_in[0];
    const float* K = (const float*)d_in[1];
    const float* V = (const float*)d_in[2];
    float* Out = (float*)d_out;                       // [4,16,1024,64]
    float* P   = (float*)d_out + (size_t)NELEM;       // [4,16,1024,1024]

    const size_t need = (size_t)NELEM * 2 * 2;        // Kb + Vt, bf16
    if (ws_size >= need) {
        bf16* Kb = (bf16*)d_ws;
        bf16* Vt = Kb + NELEM;
        prep_kv<<<dim3(4096), dim3(256), 0, stream>>>(K, V, Kb, Vt);
        sdpa_main<<<dim3(1024), dim3(256), 0, stream>>>(Q, Kb, Vt, Out, P);
    } else {
        sdpa_fused<<<dim3(16, 64), dim3(256), 0, stream>>>(Q, K, V, Out, P);
    }
}

// Round 11
// 115.998 us; speedup vs baseline: 1.1418x; 1.1418x over previous
//
#include <hip/hip_runtime.h>
#include <hip/hip_bf16.h>

// Problem constants (fixed by the reference): B=4, H=16, S=1024, D=64.
#define B_N 4
#define H_N 16
#define S_N 1024
#define D_N 64
#define NELEM (B_N * H_N * S_N * D_N)   // 4194304 elements per tensor

typedef __bf16 bf16;
typedef bf16  bf16x4 __attribute__((ext_vector_type(4)));
typedef bf16  bf16x8 __attribute__((ext_vector_type(8)));
typedef float f32x4  __attribute__((ext_vector_type(4)));
typedef unsigned int u32x2 __attribute__((ext_vector_type(2)));

#define AS1 __attribute__((address_space(1)))
#define AS3 __attribute__((address_space(3)))
// global->LDS DMA, 16B per lane; LDS dest = wave-uniform base + lane*16 (m104)
#define GLL16(gp, lp) __builtin_amdgcn_global_load_lds((const AS1 void*)(gp), (AS3 void*)(lp), 16, 0, 0)

// ============================================================================
// Prep (one kernel): fp32 -> bf16 swizzled copies of K and V into d_ws.
//  Kb[bh][k][d]  16B slots within each 128B row XORed by (k&7)
//  Vt[bh][d][k]  transposed; within each 64-k chunk, slots XORed by (d&7)
// ============================================================================
__global__ __launch_bounds__(256)
void prep_kv(const float* __restrict__ K, const float* __restrict__ V,
             bf16* __restrict__ Kb, bf16* __restrict__ Vt)
{
    const int b = blockIdx.x;
    if (b < 2048) {                        // ---- K: swizzled bf16 copy ----
        int t = b * 256 + threadIdx.x;     // 8 elems per thread
        int row = t >> 3, sub = t & 7;     // row = bh*S + k; sub = 16B slot
        const float* src = K + (size_t)row * 64 + sub * 8;
        float4 f0 = *(const float4*)src;
        float4 f1 = *(const float4*)(src + 4);
        bf16x8 o;
        o[0] = (bf16)f0.x; o[1] = (bf16)f0.y; o[2] = (bf16)f0.z; o[3] = (bf16)f0.w;
        o[4] = (bf16)f1.x; o[5] = (bf16)f1.y; o[6] = (bf16)f1.z; o[7] = (bf16)f1.w;
        int slot = sub ^ (row & 7);
        *(bf16x8*)(Kb + (size_t)row * 64 + slot * 8) = o;
    } else {                               // ---- V: transpose + swizzle ----
        int wid  = (b - 2048) * 4 + (threadIdx.x >> 6);
        int lane = threadIdx.x & 63;       // lane = d
        int bh = wid >> 7, chunk = wid & 127;   // 128 chunks of 8 k-rows
        const float* src = V + (size_t)bh * S_N * D_N + (size_t)chunk * 8 * 64 + lane;
        bf16x8 o;
#pragma unroll
        for (int j = 0; j < 8; ++j) o[j] = (bf16)src[j * 64];
        int slot = (chunk & 7) ^ (lane & 7);
        bf16* dst = Vt + (size_t)bh * D_N * S_N + (size_t)lane * S_N
                       + (chunk >> 3) * 64 + slot * 8;
        *(bf16x8*)dst = o;
    }
}

// ============================================================================
// Pass A as a standalone k-split reduction: grid 4096 = (bh, qtile, quarter).
// No LDS, no barriers: QK^T B-fragments read DIRECTLY from global Kb (L2-
// resident, same XOR addressing as the LDS path since row&7 == l16&7).
// Writes partial[((bh*16+qtile)*64 + q)*4 + quarter] — every slot written
// every call (deterministic, no atomics, overwrites 0xAA poison).
// ============================================================================
__global__ __launch_bounds__(256)
void pass_a(const float* __restrict__ Qf, const bf16* __restrict__ Kb,
            float* __restrict__ partial)
{
    const int bid = blockIdx.x;
    const int swz = (bid & 7) * 512 + (bid >> 3);   // XCD-bijective (4096%8==0)
    const int bh = swz >> 6, qtile = (swz >> 2) & 15, quarter = swz & 3;

    const int tid = threadIdx.x;
    const int wave = tid >> 6, lane = tid & 63;
    const int l16 = lane & 15, lgrp = lane >> 4;
    const int swx = (l16 & 7) << 4;

    const float* Qp = Qf + (size_t)bh * S_N * D_N;
    const char*  Kp = (const char*)(Kb + (size_t)bh * S_N * D_N);

    // Q A-fragments (scaled): a[j] = Q[q=l16-row][k=lgrp*8+j]
    const int qrow = qtile * 64 + wave * 16 + l16;
    bf16x8 aq[2];
#pragma unroll
    for (int ds = 0; ds < 2; ++ds) {
        const float* src = Qp + (size_t)qrow * 64 + ds * 32 + lgrp * 8;
        float4 f0 = *(const float4*)src;
        float4 f1 = *(const float4*)(src + 4);
        aq[ds][0] = (bf16)(f0.x * 0.125f); aq[ds][1] = (bf16)(f0.y * 0.125f);
        aq[ds][2] = (bf16)(f0.z * 0.125f); aq[ds][3] = (bf16)(f0.w * 0.125f);
        aq[ds][4] = (bf16)(f1.x * 0.125f); aq[ds][5] = (bf16)(f1.y * 0.125f);
        aq[ds][6] = (bf16)(f1.z * 0.125f); aq[ds][7] = (bf16)(f1.w * 0.125f);
    }

    float lsum[4] = {0.f, 0.f, 0.f, 0.f};
#pragma unroll
    for (int t2 = 0; t2 < 4; ++t2) {                // 4 x 64-k tiles = 256 k
        const int kt = quarter * 256 + t2 * 64;
#pragma unroll
        for (int kb = 0; kb < 4; ++kb) {
            f32x4 acc = (f32x4){0.f, 0.f, 0.f, 0.f};
#pragma unroll
            for (int ds = 0; ds < 2; ++ds) {
                // row = kt+kb*16+l16; row&7 == l16&7 -> same swx XOR as LDS path
                bf16x8 bk = *(const bf16x8*)(Kp
                            + (size_t)(kt + kb * 16 + l16) * 128
                            + ((ds * 64 + lgrp * 16) ^ swx));
                acc = __builtin_amdgcn_mfma_f32_16x16x32_bf16(aq[ds], bk, acc, 0, 0, 0);
            }
#pragma unroll
            for (int r = 0; r < 4; ++r) lsum[r] += __expf(acc[r]);
        }
    }
#pragma unroll
    for (int r = 0; r < 4; ++r) {
        float s = lsum[r];
        s += __shfl_xor(s, 1, 64);
        s += __shfl_xor(s, 2, 64);
        s += __shfl_xor(s, 4, 64);
        s += __shfl_xor(s, 8, 64);
        lsum[r] = s;
    }
    if (l16 == 0) {
        float* pb = partial + ((size_t)(bh * 16 + qtile) * 64 + wave * 16 + lgrp * 4) * 4
                            + quarter;
#pragma unroll
        for (int r = 0; r < 4; ++r) pb[r * 4] = lsum[r];
    }
}

// ============================================================================
// Main kernel = round-9 pass B verbatim: rl from ws partials, V+K dbuf
// staging via GLL16, 1 barrier/iter, QK^T recompute, Pt_lds tr_read PV,
// coalesced P/O stores.
// ============================================================================
__global__ __launch_bounds__(256)
void sdpa_main(const float* __restrict__ Qf, const bf16* __restrict__ Kb,
               const bf16* __restrict__ Vt, const float* __restrict__ partial,
               float* __restrict__ Og, float* __restrict__ Pg)
{
    __shared__ __attribute__((aligned(128))) bf16 K_lds[2][4096];   // 16KB
    __shared__ __attribute__((aligned(128))) bf16 V_lds[2][4096];   // 16KB
    __shared__ __attribute__((aligned(128))) bf16 Pt_lds[4][1024];  // 8KB

    const int bid = blockIdx.x;
    const int swz = (bid & 7) * 128 + (bid >> 3);   // XCD-bijective (1024%8==0)
    const int bh = swz >> 4, qtile = swz & 15;

    const int tid = threadIdx.x;
    const int wave = tid >> 6, lane = tid & 63;
    const int l16 = lane & 15, lgrp = lane >> 4;
    const int swx = (l16 & 7) << 4;

    const float* Qp = Qf + (size_t)bh * S_N * D_N;
    const bf16* Kp = Kb + (size_t)bh * S_N * D_N;
    const bf16* Vp = Vt + (size_t)bh * D_N * S_N;
    float* Op = Og + (size_t)bh * S_N * D_N;
    float* Pp = Pg + (size_t)bh * S_N * S_N;

    // Q A-fragments from fp32, scaled: a[j] = Q[q=l16][k=lgrp*8+j]
    const int qrow = qtile * 64 + wave * 16 + l16;
    bf16x8 aq[2];
#pragma unroll
    for (int ds = 0; ds < 2; ++ds) {
        const float* src = Qp + (size_t)qrow * 64 + ds * 32 + lgrp * 8;
        float4 f0 = *(const float4*)src;
        float4 f1 = *(const float4*)(src + 4);
        aq[ds][0] = (bf16)(f0.x * 0.125f); aq[ds][1] = (bf16)(f0.y * 0.125f);
        aq[ds][2] = (bf16)(f0.z * 0.125f); aq[ds][3] = (bf16)(f0.w * 0.125f);
        aq[ds][4] = (bf16)(f1.x * 0.125f); aq[ds][5] = (bf16)(f1.y * 0.125f);
        aq[ds][6] = (bf16)(f1.z * 0.125f); aq[ds][7] = (bf16)(f1.w * 0.125f);
    }

    // rl from pass_a partials: lane reads float4 (4 quarters) per row.
    float rl[4];
    {
        const float* pb = partial + ((size_t)(bh * 16 + qtile) * 64 + wave * 16 + lgrp * 4) * 4;
#pragma unroll
        for (int r = 0; r < 4; ++r) {
            float4 p4 = *(const float4*)(pb + r * 4);
            rl[r] = 1.0f / (p4.x + p4.y + p4.z + p4.w);
        }
    }

    auto stage_k = [&](int kt, bf16* dst) {
        const bf16* gk = Kp + (size_t)kt * 64;
        GLL16(gk + (wave    ) * 512 + lane * 8, dst + (wave    ) * 512);
        GLL16(gk + (wave + 4) * 512 + lane * 8, dst + (wave + 4) * 512);
    };
    auto stage_v = [&](int kt, bf16* dst) {
        const int dr = lane >> 3, c7 = lane & 7;   // rows are d, 128B slices
        GLL16(Vp + (size_t)((wave    ) * 8 + dr) * S_N + kt + c7 * 8, dst + (wave    ) * 512);
        GLL16(Vp + (size_t)((wave + 4) * 8 + dr) * S_N + kt + c7 * 8, dst + (wave + 4) * 512);
    };

    auto scores = [&](const bf16* base, f32x4 (&acc)[4]) {
#pragma unroll
        for (int kb = 0; kb < 4; ++kb) {
            acc[kb] = (f32x4){0.f, 0.f, 0.f, 0.f};
#pragma unroll
            for (int ds = 0; ds < 2; ++ds) {
                bf16x8 bk = *(const bf16x8*)((const char*)base
                            + (kb * 16 + l16) * 128
                            + ((ds * 64 + lgrp * 16) ^ swx));
                acc[kb] = __builtin_amdgcn_mfma_f32_16x16x32_bf16(aq[ds], bk, acc[kb], 0, 0, 0);
            }
        }
    };

    f32x4 oacc[4];
#pragma unroll
    for (int db = 0; db < 4; ++db) oacc[db] = (f32x4){0.f, 0.f, 0.f, 0.f};

    const unsigned ptoff = (unsigned)(uintptr_t)(AS3 bf16*)(&Pt_lds[wave][0]);
    const int qg = qtile * 64 + wave * 16 + l16;

    stage_k(0, &K_lds[0][0]);
    stage_v(0, &V_lds[0][0]);
    __syncthreads();
    for (int t = 0; t < 16; ++t) {
        const int kt = t * 64, buf = t & 1;

        f32x4 acc[4];
        scores(&K_lds[buf][0], acc);

        // Prefetch t+1 into the other buffers; completion guaranteed by the
        // __syncthreads drain at iter end; latency hides under exp+PV below.
        if (t < 15) {
            stage_k(kt + 64, &K_lds[buf ^ 1][0]);
            stage_v(kt + 64, &V_lds[buf ^ 1][0]);
        }

        // p = exp(s)*rl -> bf16; write P^T[k][q] as packed 4-q ds_write_b64
#pragma unroll
        for (int kb = 0; kb < 4; ++kb) {
            bf16x4 pk;
#pragma unroll
            for (int r = 0; r < 4; ++r) pk[r] = (bf16)(__expf(acc[kb][r]) * rl[r]);
            *(bf16x4*)((char*)&Pt_lds[wave][0] + (kb * 16 + l16) * 32 + lgrp * 8) = pk;
        }
        asm volatile("s_waitcnt lgkmcnt(0)" ::: "memory");  // writes done before tr reads

        const bf16* vb = &V_lds[buf][0];
#pragma unroll
        for (int ks = 0; ks < 2; ++ks) {
            // V B-fragments (swizzled row-major [d][k] reads, 2-way free)
            bf16x8 bv0 = *(const bf16x8*)((const char*)vb + (l16     ) * 128 + ((ks * 64 + lgrp * 16) ^ swx));
            bf16x8 bv1 = *(const bf16x8*)((const char*)vb + (16 + l16) * 128 + ((ks * 64 + lgrp * 16) ^ swx));
            bf16x8 bv2 = *(const bf16x8*)((const char*)vb + (32 + l16) * 128 + ((ks * 64 + lgrp * 16) ^ swx));
            bf16x8 bv3 = *(const bf16x8*)((const char*)vb + (48 + l16) * 128 + ((ks * 64 + lgrp * 16) ^ swx));

            // PV A-fragment via HW transpose read (region per 16-lane group,
            // per-lane addr slot (addr&127)>>3 picks column q=l16).
            u32x2 t0, t1;
            unsigned a = ptoff + ks * 1024 + lgrp * 256 + l16 * 8;
            asm volatile("ds_read_b64_tr_b16 %0, %2\n\t"
                         "ds_read_b64_tr_b16 %1, %2 offset:128"
                         : "=&v"(t0), "=&v"(t1) : "v"(a));
            asm volatile("s_waitcnt lgkmcnt(0)" ::: "memory");
            __builtin_amdgcn_sched_barrier(0);   // rule 18: keep MFMA below the wait

            bf16x8 ap;
            ((unsigned*)&ap)[0] = t0[0]; ((unsigned*)&ap)[1] = t0[1];
            ((unsigned*)&ap)[2] = t1[0]; ((unsigned*)&ap)[3] = t1[1];

            // Global P store: lane holds 8 contiguous k for row q=l16 -> 2x f32x4
            float4 o0, o1;
            o0.x = __uint_as_float(t0[0] << 16);
            o0.y = __uint_as_float(t0[0] & 0xffff0000u);
            o0.z = __uint_as_float(t0[1] << 16);
            o0.w = __uint_as_float(t0[1] & 0xffff0000u);
            o1.x = __uint_as_float(t1[0] << 16);
            o1.y = __uint_as_float(t1[0] & 0xffff0000u);
            o1.z = __uint_as_float(t1[1] << 16);
            o1.w = __uint_as_float(t1[1] & 0xffff0000u);
            float* pp = Pp + (size_t)qg * S_N + kt + ks * 32 + lgrp * 8;
            *(float4*)pp = o0;
            *(float4*)(pp + 4) = o1;

            oacc[0] = __builtin_amdgcn_mfma_f32_16x16x32_bf16(ap, bv0, oacc[0], 0, 0, 0);
            oacc[1] = __builtin_amdgcn_mfma_f32_16x16x32_bf16(ap, bv1, oacc[1], 0, 0, 0);
            oacc[2] = __builtin_amdgcn_mfma_f32_16x16x32_bf16(ap, bv2, oacc[2], 0, 0, 0);
            oacc[3] = __builtin_amdgcn_mfma_f32_16x16x32_bf16(ap, bv3, oacc[3], 0, 0, 0);
        }
        __syncthreads();   // joins waves AND drains vmcnt -> prefetch complete
    }

    const int qb0 = qtile * 64 + wave * 16 + lgrp * 4;
#pragma unroll
    for (int db = 0; db < 4; ++db)
#pragma unroll
        for (int r = 0; r < 4; ++r)
            Op[(size_t)(qb0 + r) * D_N + db * 16 + l16] = oacc[db][r];
}

// ============================================================================
// Round-1 fallback (fp32 inputs, no workspace) — used only if ws too small.
// ============================================================================
__global__ __launch_bounds__(256)
void sdpa_fused(const float* __restrict__ Qg, const float* __restrict__ Kg,
                const float* __restrict__ Vg, float* __restrict__ Og,
                float* __restrict__ Pg)
{
    constexpr int LDP = 72;
    __shared__ bf16 K_lds [64][LDP];
    __shared__ bf16 Vt_lds[64][LDP];
    __shared__ bf16 P_lds [4][16][LDP];

    const int qtile = blockIdx.x;
    const int bh    = blockIdx.y;
    const int tid   = threadIdx.x;
    const int wave  = tid >> 6;
    const int lane  = tid & 63;
    const int l16   = lane & 15;
    const int lgrp  = lane >> 4;

    const float* Qp = Qg + (size_t)bh * S_N * D_N;
    const float* Kp = Kg + (size_t)bh * S_N * D_N;
    const float* Vp = Vg + (size_t)bh * S_N * D_N;
    float* Op = Og + (size_t)bh * S_N * D_N;
    float* Pp = Pg + (size_t)bh * S_N * S_N;

    const int qrow = qtile * 64 + wave * 16 + l16;
    bf16x8 aq[2];
#pragma unroll
    for (int ds = 0; ds < 2; ++ds) {
        const float* src = Qp + qrow * D_N + ds * 32 + lgrp * 8;
        float4 f0 = *(const float4*)(src);
        float4 f1 = *(const float4*)(src + 4);
        aq[ds][0] = (bf16)(f0.x * 0.125f); aq[ds][1] = (bf16)(f0.y * 0.125f);
        aq[ds][2] = (bf16)(f0.z * 0.125f); aq[ds][3] = (bf16)(f0.w * 0.125f);
        aq[ds][4] = (bf16)(f1.x * 0.125f); aq[ds][5] = (bf16)(f1.y * 0.125f);
        aq[ds][6] = (bf16)(f1.z * 0.125f); aq[ds][7] = (bf16)(f1.w * 0.125f);
    }

    auto stage_k = [&](int kt) {
#pragma unroll
        for (int i = 0; i < 4; ++i) {
            int slot = tid + i * 256;
            int row = slot >> 4, c4 = slot & 15;
            float4 f = *(const float4*)(Kp + (kt + row) * D_N + c4 * 4);
            bf16x4 pk = {(bf16)f.x, (bf16)f.y, (bf16)f.z, (bf16)f.w};
            *(bf16x4*)&K_lds[row][c4 * 4] = pk;
        }
    };
    auto stage_v = [&](int kt) {
#pragma unroll
        for (int i = 0; i < 4; ++i) {
            int slot = tid + i * 256;
            int row = slot >> 4, c4 = slot & 15;
            float4 f = *(const float4*)(Vp + (kt + row) * D_N + c4 * 4);
            Vt_lds[c4 * 4 + 0][row] = (bf16)f.x;
            Vt_lds[c4 * 4 + 1][row] = (bf16)f.y;
            Vt_lds[c4 * 4 + 2][row] = (bf16)f.z;
            Vt_lds[c4 * 4 + 3][row] = (bf16)f.w;
        }
    };
    auto compute_scores = [&](f32x4 (&acc)[4]) {
#pragma unroll
        for (int kb = 0; kb < 4; ++kb) {
            acc[kb] = (f32x4){0.f, 0.f, 0.f, 0.f};
#pragma unroll
            for (int ds = 0; ds < 2; ++ds) {
                bf16x8 bk = *(const bf16x8*)&K_lds[kb * 16 + l16][ds * 32 + lgrp * 8];
                acc[kb] = __builtin_amdgcn_mfma_f32_16x16x32_bf16(aq[ds], bk, acc[kb], 0, 0, 0);
            }
        }
    };

    float lsum[4] = {0.f, 0.f, 0.f, 0.f};
    for (int kt = 0; kt < S_N; kt += 64) {
        __syncthreads();
        stage_k(kt);
        __syncthreads();
        f32x4 acc[4];
        compute_scores(acc);
#pragma unroll
        for (int kb = 0; kb < 4; ++kb)
#pragma unroll
            for (int r = 0; r < 4; ++r) lsum[r] += __expf(acc[kb][r]);
    }
    float rl[4];
#pragma unroll
    for (int r = 0; r < 4; ++r) {
        float s = lsum[r];
        s += __shfl_xor(s, 1, 64);
        s += __shfl_xor(s, 2, 64);
        s += __shfl_xor(s, 4, 64);
        s += __shfl_xor(s, 8, 64);
        rl[r] = 1.0f / s;
    }

    f32x4 oacc[4];
#pragma unroll
    for (int db = 0; db < 4; ++db) oacc[db] = (f32x4){0.f, 0.f, 0.f, 0.f};
    const int qb0 = qtile * 64 + wave * 16 + lgrp * 4;

    for (int kt = 0; kt < S_N; kt += 64) {
        __syncthreads();
        stage_k(kt);
        stage_v(kt);
        __syncthreads();

        f32x4 acc[4];
        compute_scores(acc);
#pragma unroll
        for (int kb = 0; kb < 4; ++kb) {
#pragma unroll
            for (int r = 0; r < 4; ++r) {
                float p = __expf(acc[kb][r]) * rl[r];
                Pp[(size_t)(qb0 + r) * S_N + (kt + kb * 16 + l16)] = p;
                P_lds[wave][lgrp * 4 + r][kb * 16 + l16] = (bf16)p;
            }
        }
#pragma unroll
        for (int ks = 0; ks < 2; ++ks) {
            bf16x8 ap = *(const bf16x8*)&P_lds[wave][l16][ks * 32 + lgrp * 8];
#pragma unroll
            for (int db = 0; db < 4; ++db) {
                bf16x8 bv = *(const bf16x8*)&Vt_lds[db * 16 + l16][ks * 32 + lgrp * 8];
                oacc[db] = __builtin_amdgcn_mfma_f32_16x16x32_bf16(ap, bv, oacc[db], 0, 0, 0);
            }
        }
    }

#pragma unroll
    for (int db = 0; db < 4; ++db)
#pragma unroll
        for (int r = 0; r < 4; ++r)
            Op[(size_t)(qb0 + r) * D_N + db * 16 + l16] = oacc[db][r];
}

extern "C" void kernel_launch(void* const* d_in, const int* in_sizes, int n_in,
                              void* d_out, int out_size, void* d_ws, size_t ws_size,
                              hipStream_t stream) {
    const float* Q = (const float*)d_in[0];
    const float* K = (const float*)d_in[1];
    const float* V = (const float*)d_in[2];
    float* Out = (float*)d_out;                       // [4,16,1024,64]
    float* P   = (float*)d_out + (size_t)NELEM;       // [4,16,1024,1024]

    // ws layout: Kb (bf16, 8MB) | Vt (bf16, 8MB) | partial (fp32, 1MB)
    const size_t need = (size_t)NELEM * 2 * 2 + (size_t)64 * 16 * 64 * 4 * 4;
    if (ws_size >= need) {
        bf16* Kb = (bf16*)d_ws;
        bf16* Vt = Kb + NELEM;
        float* partial = (float*)(Vt + NELEM);
        prep_kv<<<dim3(4096), dim3(256), 0, stream>>>(K, V, Kb, Vt);
        pass_a<<<dim3(4096), dim3(256), 0, stream>>>(Q, Kb, partial);
        sdpa_main<<<dim3(1024), dim3(256), 0, stream>>>(Q, Kb, Vt, partial, Out, P);
    } else {
        sdpa_fused<<<dim3(16, 64), dim3(256), 0, stream>>>(Q, K, V, Out, P);
    }
}

// Round 12
// 96.866 us; speedup vs baseline: 1.3673x; 1.1975x over previous
//
#include <hip/hip_runtime.h>
#include <hip/hip_bf16.h>

// Problem constants (fixed by the reference): B=4, H=16, S=1024, D=64.
#define B_N 4
#define H_N 16
#define S_N 1024
#define D_N 64
#define NELEM (B_N * H_N * S_N * D_N)   // 4194304 elements per tensor

typedef __bf16 bf16;
typedef bf16  bf16x4 __attribute__((ext_vector_type(4)));
typedef bf16  bf16x8 __attribute__((ext_vector_type(8)));
typedef float f32x4  __attribute__((ext_vector_type(4)));
typedef unsigned int u32x2 __attribute__((ext_vector_type(2)));

#define AS1 __attribute__((address_space(1)))
#define AS3 __attribute__((address_space(3)))
// global->LDS DMA, 16B per lane; LDS dest = wave-uniform base + lane*16 (m104)
#define GLL16(gp, lp) __builtin_amdgcn_global_load_lds((const AS1 void*)(gp), (AS3 void*)(lp), 16, 0, 0)

// ============================================================================
// Prep (one kernel): fp32 -> bf16 swizzled copies of K and V into d_ws.
//  Kb[bh][k][d]  16B slots within each 128B row XORed by (k&7)
//  Vt[bh][d][k]  transposed; within each 64-k chunk, slots XORed by (d&7)
// ============================================================================
__global__ __launch_bounds__(256)
void prep_kv(const float* __restrict__ K, const float* __restrict__ V,
             bf16* __restrict__ Kb, bf16* __restrict__ Vt)
{
    const int b = blockIdx.x;
    if (b < 2048) {                        // ---- K: swizzled bf16 copy ----
        int t = b * 256 + threadIdx.x;     // 8 elems per thread
        int row = t >> 3, sub = t & 7;     // row = bh*S + k; sub = 16B slot
        const float* src = K + (size_t)row * 64 + sub * 8;
        float4 f0 = *(const float4*)src;
        float4 f1 = *(const float4*)(src + 4);
        bf16x8 o;
        o[0] = (bf16)f0.x; o[1] = (bf16)f0.y; o[2] = (bf16)f0.z; o[3] = (bf16)f0.w;
        o[4] = (bf16)f1.x; o[5] = (bf16)f1.y; o[6] = (bf16)f1.z; o[7] = (bf16)f1.w;
        int slot = sub ^ (row & 7);
        *(bf16x8*)(Kb + (size_t)row * 64 + slot * 8) = o;
    } else {                               // ---- V: transpose + swizzle ----
        int wid  = (b - 2048) * 4 + (threadIdx.x >> 6);
        int lane = threadIdx.x & 63;       // lane = d
        int bh = wid >> 7, chunk = wid & 127;   // 128 chunks of 8 k-rows
        const float* src = V + (size_t)bh * S_N * D_N + (size_t)chunk * 8 * 64 + lane;
        bf16x8 o;
#pragma unroll
        for (int j = 0; j < 8; ++j) o[j] = (bf16)src[j * 64];
        int slot = (chunk & 7) ^ (lane & 7);
        bf16* dst = Vt + (size_t)bh * D_N * S_N + (size_t)lane * S_N
                       + (chunk >> 3) * 64 + slot * 8;
        *(bf16x8*)dst = o;
    }
}

// ============================================================================
// Main fused kernel: 1 block = 64 q-rows (4 waves x 16), two passes over K.
// Round 12 = round 9 (96.2µs, PASS) with ONE change: pass B's iteration
// barrier is s_waitcnt vmcnt(8) + raw s_barrier instead of __syncthreads.
// vmcnt retires in order; at the barrier outstanding = [GLL16(t+1) x4,
// P-stores(t) x8], so vmcnt(8) completes the staging while this iteration's
// P stores stay in flight ACROSS the barrier (T4: never drain to 0 mid-loop).
// Round-9's __syncthreads drained vmcnt(0) -> waited for P-store commit
// every iteration (the exposed ~600-900cy store-ack was the r9 gap).
// ============================================================================
__global__ __launch_bounds__(256)
void sdpa_main(const float* __restrict__ Qf, const bf16* __restrict__ Kb,
               const bf16* __restrict__ Vt, float* __restrict__ Og,
               float* __restrict__ Pg)
{
    __shared__ __attribute__((aligned(128))) bf16 K_lds[2][4096];   // 16KB
    __shared__ __attribute__((aligned(128))) bf16 V_lds[2][4096];   // 16KB
    __shared__ __attribute__((aligned(128))) bf16 Pt_lds[4][1024];  // 8KB

    // XCD-bijective swizzle: 16 q-tiles of each bh land on one XCD (nwg=1024%8==0)
    const int bid = blockIdx.x;
    const int swz = (bid & 7) * 128 + (bid >> 3);
    const int bh = swz >> 4, qtile = swz & 15;

    const int tid = threadIdx.x;
    const int wave = tid >> 6, lane = tid & 63;
    const int l16 = lane & 15, lgrp = lane >> 4;
    const int swx = (l16 & 7) << 4;     // byte XOR for swizzled LDS reads

    const float* Qp = Qf + (size_t)bh * S_N * D_N;
    const bf16* Kp = Kb + (size_t)bh * S_N * D_N;
    const bf16* Vp = Vt + (size_t)bh * D_N * S_N;
    float* Op = Og + (size_t)bh * S_N * D_N;
    float* Pp = Pg + (size_t)bh * S_N * S_N;

    // Q A-fragments from fp32, scaled by 1/sqrt(64): a[j]=Q[q=l16][k=lgrp*8+j]
    const int qrow = qtile * 64 + wave * 16 + l16;
    bf16x8 aq[2];
#pragma unroll
    for (int ds = 0; ds < 2; ++ds) {
        const float* src = Qp + (size_t)qrow * 64 + ds * 32 + lgrp * 8;
        float4 f0 = *(const float4*)src;
        float4 f1 = *(const float4*)(src + 4);
        aq[ds][0] = (bf16)(f0.x * 0.125f); aq[ds][1] = (bf16)(f0.y * 0.125f);
        aq[ds][2] = (bf16)(f0.z * 0.125f); aq[ds][3] = (bf16)(f0.w * 0.125f);
        aq[ds][4] = (bf16)(f1.x * 0.125f); aq[ds][5] = (bf16)(f1.y * 0.125f);
        aq[ds][6] = (bf16)(f1.z * 0.125f); aq[ds][7] = (bf16)(f1.w * 0.125f);
    }

    // Staging: one 64x64 bf16 tile = 8KB = 2 GLL16 per wave (4 waves)
    auto stage_k = [&](int kt, bf16* dst) {
        const bf16* gk = Kp + (size_t)kt * 64;
        GLL16(gk + (wave    ) * 512 + lane * 8, dst + (wave    ) * 512);
        GLL16(gk + (wave + 4) * 512 + lane * 8, dst + (wave + 4) * 512);
    };
    // 128-k double tile (16KB contiguous) into two 8KB buffers
    auto stage_k2 = [&](int kt, bf16* dst0, bf16* dst1) {
        const bf16* gk = Kp + (size_t)kt * 64;
        GLL16(gk + (wave     ) * 512 + lane * 8, dst0 + (wave    ) * 512);
        GLL16(gk + (wave + 4 ) * 512 + lane * 8, dst0 + (wave + 4) * 512);
        GLL16(gk + (wave + 8 ) * 512 + lane * 8, dst1 + (wave    ) * 512);
        GLL16(gk + (wave + 12) * 512 + lane * 8, dst1 + (wave + 4) * 512);
    };
    auto stage_v = [&](int kt, bf16* dst) {
        const int dr = lane >> 3, c7 = lane & 7;   // rows are d, 128B slices
        GLL16(Vp + (size_t)((wave    ) * 8 + dr) * S_N + kt + c7 * 8, dst + (wave    ) * 512);
        GLL16(Vp + (size_t)((wave + 4) * 8 + dr) * S_N + kt + c7 * 8, dst + (wave + 4) * 512);
    };

    // QK^T scores for this wave's 16 q-rows vs a staged 64-row K tile.
    // C/D layout (m89): col(k) = lane&15, row(q) = (lane>>4)*4 + reg.
    auto scores = [&](const bf16* base, f32x4 (&acc)[4]) {
#pragma unroll
        for (int kb = 0; kb < 4; ++kb) {
            acc[kb] = (f32x4){0.f, 0.f, 0.f, 0.f};
#pragma unroll
            for (int ds = 0; ds < 2; ++ds) {
                bf16x8 bk = *(const bf16x8*)((const char*)base
                            + (kb * 16 + l16) * 128
                            + ((ds * 64 + lgrp * 16) ^ swx));
                acc[kb] = __builtin_amdgcn_mfma_f32_16x16x32_bf16(aq[ds], bk, acc[kb], 0, 0, 0);
            }
        }
    };

    // -------- Pass A: denominators. 128 k per iter, 1 barrier per iter. -----
    float lsum[4] = {0.f, 0.f, 0.f, 0.f};
    stage_k2(0, &K_lds[0][0], &K_lds[1][0]);
    __syncthreads();
    for (int c = 0; c < 8; ++c) {
        const bf16* b0 = (c & 1) ? &V_lds[0][0] : &K_lds[0][0];
        const bf16* b1 = (c & 1) ? &V_lds[1][0] : &K_lds[1][0];
        bf16* n0 = (c & 1) ? &K_lds[0][0] : &V_lds[0][0];
        bf16* n1 = (c & 1) ? &K_lds[1][0] : &V_lds[1][0];
        if (c < 7) stage_k2((c + 1) * 128, n0, n1);
        f32x4 acc[4];
        scores(b0, acc);
#pragma unroll
        for (int kb = 0; kb < 4; ++kb)
#pragma unroll
            for (int r = 0; r < 4; ++r) lsum[r] += __expf(acc[kb][r]);
        scores(b1, acc);
#pragma unroll
        for (int kb = 0; kb < 4; ++kb)
#pragma unroll
            for (int r = 0; r < 4; ++r) lsum[r] += __expf(acc[kb][r]);
        __syncthreads();
    }
    float rl[4];
#pragma unroll
    for (int r = 0; r < 4; ++r) {
        float s = lsum[r];
        s += __shfl_xor(s, 1, 64);
        s += __shfl_xor(s, 2, 64);
        s += __shfl_xor(s, 4, 64);
        s += __shfl_xor(s, 8, 64);
        rl[r] = 1.0f / s;
    }

    // ---- Pass B: recompute, write P, accumulate O = P V. 1 barrier/iter, ---
    // ---- counted vmcnt: P stores stay in flight across the barrier.     ----
    f32x4 oacc[4];
#pragma unroll
    for (int db = 0; db < 4; ++db) oacc[db] = (f32x4){0.f, 0.f, 0.f, 0.f};

    const unsigned ptoff = (unsigned)(uintptr_t)(AS3 bf16*)(&Pt_lds[wave][0]);
    const int qg = qtile * 64 + wave * 16 + l16;

    stage_k(0, &K_lds[0][0]);
    stage_v(0, &V_lds[0][0]);
    asm volatile("s_waitcnt vmcnt(0)" ::: "memory");
    __builtin_amdgcn_s_barrier();
    for (int t = 0; t < 16; ++t) {
        const int kt = t * 64, buf = t & 1;

        f32x4 acc[4];
        scores(&K_lds[buf][0], acc);

        // Prefetch t+1 into the other buffers (issued BEFORE this iter's P
        // stores -> in-order vmcnt lets us wait for these without draining
        // the stores). Latency hides under exp+PV below.
        if (t < 15) {
            stage_k(kt + 64, &K_lds[buf ^ 1][0]);
            stage_v(kt + 64, &V_lds[buf ^ 1][0]);
        }

        // p = exp(s)*rl -> bf16; write P^T[k][q] as packed 4-q ds_write_b64
#pragma unroll
        for (int kb = 0; kb < 4; ++kb) {
            bf16x4 pk;
#pragma unroll
            for (int r = 0; r < 4; ++r) pk[r] = (bf16)(__expf(acc[kb][r]) * rl[r]);
            *(bf16x4*)((char*)&Pt_lds[wave][0] + (kb * 16 + l16) * 32 + lgrp * 8) = pk;
        }
        asm volatile("s_waitcnt lgkmcnt(0)" ::: "memory");  // writes done before tr reads

        const bf16* vb = &V_lds[buf][0];
#pragma unroll
        for (int ks = 0; ks < 2; ++ks) {
            // V B-fragments (swizzled row-major [d][k] reads, 2-way free)
            bf16x8 bv0 = *(const bf16x8*)((const char*)vb + (l16     ) * 128 + ((ks * 64 + lgrp * 16) ^ swx));
            bf16x8 bv1 = *(const bf16x8*)((const char*)vb + (16 + l16) * 128 + ((ks * 64 + lgrp * 16) ^ swx));
            bf16x8 bv2 = *(const bf16x8*)((const char*)vb + (32 + l16) * 128 + ((ks * 64 + lgrp * 16) ^ swx));
            bf16x8 bv3 = *(const bf16x8*)((const char*)vb + (48 + l16) * 128 + ((ks * 64 + lgrp * 16) ^ swx));

            // PV A-fragment via HW transpose read (region per 16-lane group,
            // per-lane addr slot (addr&127)>>3 picks column q=l16).
            u32x2 t0, t1;
            unsigned a = ptoff + ks * 1024 + lgrp * 256 + l16 * 8;
            asm volatile("ds_read_b64_tr_b16 %0, %2\n\t"
                         "ds_read_b64_tr_b16 %1, %2 offset:128"
                         : "=&v"(t0), "=&v"(t1) : "v"(a));
            asm volatile("s_waitcnt lgkmcnt(0)" ::: "memory");
            __builtin_amdgcn_sched_barrier(0);   // rule 18: keep MFMA below the wait

            bf16x8 ap;
            ((unsigned*)&ap)[0] = t0[0]; ((unsigned*)&ap)[1] = t0[1];
            ((unsigned*)&ap)[2] = t1[0]; ((unsigned*)&ap)[3] = t1[1];

            // Global P store: lane holds 8 contiguous k for row q=l16 -> 2x f32x4
            float4 o0, o1;
            o0.x = __uint_as_float(t0[0] << 16);
            o0.y = __uint_as_float(t0[0] & 0xffff0000u);
            o0.z = __uint_as_float(t0[1] << 16);
            o0.w = __uint_as_float(t0[1] & 0xffff0000u);
            o1.x = __uint_as_float(t1[0] << 16);
            o1.y = __uint_as_float(t1[0] & 0xffff0000u);
            o1.z = __uint_as_float(t1[1] << 16);
            o1.w = __uint_as_float(t1[1] & 0xffff0000u);
            float* pp = Pp + (size_t)qg * S_N + kt + ks * 32 + lgrp * 8;
            *(float4*)pp = o0;
            *(float4*)(pp + 4) = o1;

            oacc[0] = __builtin_amdgcn_mfma_f32_16x16x32_bf16(ap, bv0, oacc[0], 0, 0, 0);
            oacc[1] = __builtin_amdgcn_mfma_f32_16x16x32_bf16(ap, bv1, oacc[1], 0, 0, 0);
            oacc[2] = __builtin_amdgcn_mfma_f32_16x16x32_bf16(ap, bv2, oacc[2], 0, 0, 0);
            oacc[3] = __builtin_amdgcn_mfma_f32_16x16x32_bf16(ap, bv3, oacc[3], 0, 0, 0);
        }

        // Counted-vmcnt barrier: outstanding (in issue order) =
        //   [P-stores(t-1) maybe][GLL16(t+1) x4][P-stores(t) x8]
        // vmcnt(8) -> GLL16(t+1) complete (and all older ops), 8 newest
        // (this iter's P stores) still in flight across the barrier.
        asm volatile("s_waitcnt vmcnt(8)" ::: "memory");
        __builtin_amdgcn_s_barrier();
    }

    const int qb0 = qtile * 64 + wave * 16 + lgrp * 4;
#pragma unroll
    for (int db = 0; db < 4; ++db)
#pragma unroll
        for (int r = 0; r < 4; ++r)
            Op[(size_t)(qb0 + r) * D_N + db * 16 + l16] = oacc[db][r];
}

// ============================================================================
// Round-1 fallback (fp32 inputs, no workspace) — used only if ws too small.
// ============================================================================
__global__ __launch_bounds__(256)
void sdpa_fused(const float* __restrict__ Qg, const float* __restrict__ Kg,
                const float* __restrict__ Vg, float* __restrict__ Og,
                float* __restrict__ Pg)
{
    constexpr int LDP = 72;
    __shared__ bf16 K_lds [64][LDP];
    __shared__ bf16 Vt_lds[64][LDP];
    __shared__ bf16 P_lds [4][16][LDP];

    const int qtile = blockIdx.x;
    const int bh    = blockIdx.y;
    const int tid   = threadIdx.x;
    const int wave  = tid >> 6;
    const int lane  = tid & 63;
    const int l16   = lane & 15;
    const int lgrp  = lane >> 4;

    const float* Qp = Qg + (size_t)bh * S_N * D_N;
    const float* Kp = Kg + (size_t)bh * S_N * D_N;
    const float* Vp = Vg + (size_t)bh * S_N * D_N;
    float* Op = Og + (size_t)bh * S_N * D_N;
    float* Pp = Pg + (size_t)bh * S_N * S_N;

    const int qrow = qtile * 64 + wave * 16 + l16;
    bf16x8 aq[2];
#pragma unroll
    for (int ds = 0; ds < 2; ++ds) {
        const float* src = Qp + qrow * D_N + ds * 32 + lgrp * 8;
        float4 f0 = *(const float4*)(src);
        float4 f1 = *(const float4*)(src + 4);
        aq[ds][0] = (bf16)(f0.x * 0.125f); aq[ds][1] = (bf16)(f0.y * 0.125f);
        aq[ds][2] = (bf16)(f0.z * 0.125f); aq[ds][3] = (bf16)(f0.w * 0.125f);
        aq[ds][4] = (bf16)(f1.x * 0.125f); aq[ds][5] = (bf16)(f1.y * 0.125f);
        aq[ds][6] = (bf16)(f1.z * 0.125f); aq[ds][7] = (bf16)(f1.w * 0.125f);
    }

    auto stage_k = [&](int kt) {
#pragma unroll
        for (int i = 0; i < 4; ++i) {
            int slot = tid + i * 256;
            int row = slot >> 4, c4 = slot & 15;
            float4 f = *(const float4*)(Kp + (kt + row) * D_N + c4 * 4);
            bf16x4 pk = {(bf16)f.x, (bf16)f.y, (bf16)f.z, (bf16)f.w};
            *(bf16x4*)&K_lds[row][c4 * 4] = pk;
        }
    };
    auto stage_v = [&](int kt) {
#pragma unroll
        for (int i = 0; i < 4; ++i) {
            int slot = tid + i * 256;
            int row = slot >> 4, c4 = slot & 15;
            float4 f = *(const float4*)(Vp + (kt + row) * D_N + c4 * 4);
            Vt_lds[c4 * 4 + 0][row] = (bf16)f.x;
            Vt_lds[c4 * 4 + 1][row] = (bf16)f.y;
            Vt_lds[c4 * 4 + 2][row] = (bf16)f.z;
            Vt_lds[c4 * 4 + 3][row] = (bf16)f.w;
        }
    };
    auto compute_scores = [&](f32x4 (&acc)[4]) {
#pragma unroll
        for (int kb = 0; kb < 4; ++kb) {
            acc[kb] = (f32x4){0.f, 0.f, 0.f, 0.f};
#pragma unroll
            for (int ds = 0; ds < 2; ++ds) {
                bf16x8 bk = *(const bf16x8*)&K_lds[kb * 16 + l16][ds * 32 + lgrp * 8];
                acc[kb] = __builtin_amdgcn_mfma_f32_16x16x32_bf16(aq[ds], bk, acc[kb], 0, 0, 0);
            }
        }
    };

    float lsum[4] = {0.f, 0.f, 0.f, 0.f};
    for (int kt = 0; kt < S_N; kt += 64) {
        __syncthreads();
        stage_k(kt);
        __syncthreads();
        f32x4 acc[4];
        compute_scores(acc);
#pragma unroll
        for (int kb = 0; kb < 4; ++kb)
#pragma unroll
            for (int r = 0; r < 4; ++r) lsum[r] += __expf(acc[kb][r]);
    }
    float rl[4];
#pragma unroll
    for (int r = 0; r < 4; ++r) {
        float s = lsum[r];
        s += __shfl_xor(s, 1, 64);
        s += __shfl_xor(s, 2, 64);
        s += __shfl_xor(s, 4, 64);
        s += __shfl_xor(s, 8, 64);
        rl[r] = 1.0f / s;
    }

    f32x4 oacc[4];
#pragma unroll
    for (int db = 0; db < 4; ++db) oacc[db] = (f32x4){0.f, 0.f, 0.f, 0.f};
    const int qb0 = qtile * 64 + wave * 16 + lgrp * 4;

    for (int kt = 0; kt < S_N; kt += 64) {
        __syncthreads();
        stage_k(kt);
        stage_v(kt);
        __syncthreads();

        f32x4 acc[4];
        compute_scores(acc);
#pragma unroll
        for (int kb = 0; kb < 4; ++kb) {
#pragma unroll
            for (int r = 0; r < 4; ++r) {
                float p = __expf(acc[kb][r]) * rl[r];
                Pp[(size_t)(qb0 + r) * S_N + (kt + kb * 16 + l16)] = p;
                P_lds[wave][lgrp * 4 + r][kb * 16 + l16] = (bf16)p;
            }
        }
#pragma unroll
        for (int ks = 0; ks < 2; ++ks) {
            bf16x8 ap = *(const bf16x8*)&P_lds[wave][l16][ks * 32 + lgrp * 8];
#pragma unroll
            for (int db = 0; db < 4; ++db) {
                bf16x8 bv = *(const bf16x8*)&Vt_lds[db * 16 + l16][ks * 32 + lgrp * 8];
                oacc[db] = __builtin_amdgcn_mfma_f32_16x16x32_bf16(ap, bv, oacc[db], 0, 0, 0);
            }
        }
    }

#pragma unroll
    for (int db = 0; db < 4; ++db)
#pragma unroll
        for (int r = 0; r < 4; ++r)
            Op[(size_t)(qb0 + r) * D_N + db * 16 + l16] = oacc[db][r];
}

extern "C" void kernel_launch(void* const* d_in, const int* in_sizes, int n_in,
                              void* d_out, int out_size, void* d_ws, size_t ws_size,
                              hipStream_t stream) {
    const float* Q = (const float*)d_in[0];
    const float* K = (const float*)d_in[1];
    const float* V = (const float*)d_in[2];
    float* Out = (float*)d_out;                       // [4,16,1024,64]
    float* P   = (float*)d_out + (size_t)NELEM;       // [4,16,1024,1024]

    const size_t need = (size_t)NELEM * 2 * 2;        // Kb + Vt, bf16
    if (ws_size >= need) {
        bf16* Kb = (bf16*)d_ws;
        bf16* Vt = Kb + NELEM;
        prep_kv<<<dim3(4096), dim3(256), 0, stream>>>(K, V, Kb, Vt);
        sdpa_main<<<dim3(1024), dim3(256), 0, stream>>>(Q, Kb, Vt, Out, P);
    } else {
        sdpa_fused<<<dim3(16, 64), dim3(256), 0, stream>>>(Q, K, V, Out, P);
    }
}